// Round 6
// baseline (3145.882 us; speedup 1.0000x reference)
//
#include <hip/hip_runtime.h>
#include <hip/hip_bf16.h>

// ---------- helpers ----------
__device__ __forceinline__ float gelu_exact(float x) {
    return 0.5f * x * (1.0f + erff(x * 0.70710678118654752440f));
}

// ---------- naive GEMM: C[M,256] = act(concat(A1,A2)[M,KSZ] @ W[KSZ,256] + bias) ----------
// Block = 4 consecutive rows of A staged in LDS; thread = one output column.
// A reads broadcast from LDS, W reads coalesced. f32 throughout.
template<int KSZ, int ACT>
__global__ __launch_bounds__(256) void gemm_naive(
    const float* __restrict__ A1, const float* __restrict__ A2,
    const float* __restrict__ W, const float* __restrict__ bias,
    float* __restrict__ C, int M)
{
    __shared__ float As[4][KSZ];
    const int m0 = blockIdx.x * 4;
    const int n = threadIdx.x;

    #pragma unroll
    for (int r = 0; r < 4; ++r) {
        int m = m0 + r;
        for (int k = threadIdx.x; k < KSZ; k += 256) {
            float v = 0.f;
            if (m < M) v = (k < 256) ? A1[(size_t)m * 256 + k]
                                     : A2[(size_t)m * 256 + (k - 256)];
            As[r][k] = v;
        }
    }
    __syncthreads();

    float c0 = 0.f, c1 = 0.f, c2 = 0.f, c3 = 0.f;
    for (int k = 0; k < KSZ; ++k) {
        float w = W[(size_t)k * 256 + n];
        c0 += As[0][k] * w;
        c1 += As[1][k] * w;
        c2 += As[2][k] * w;
        c3 += As[3][k] * w;
    }

    float b = bias ? bias[n] : 0.f;
    float cc[4] = {c0 + b, c1 + b, c2 + b, c3 + b};
    #pragma unroll
    for (int r = 0; r < 4; ++r) {
        int m = m0 + r;
        if (m >= M) continue;
        float v = cc[r];
        if (ACT) v = gelu_exact(v);
        C[(size_t)m * 256 + n] = v;
    }
}

// ---------- edge pass A: scores + positive atomicMax into smax ----------
// one wave (64 lanes) per edge; lane handles dims [4*lane, 4*lane+4); head = lane>>4
__global__ __launch_bounds__(256) void edge_scores(
    const float* __restrict__ Q, const float* __restrict__ K,
    const int* __restrict__ tgt, const int* __restrict__ src,
    const float* __restrict__ nw, float* __restrict__ scores,
    float* __restrict__ smax, int E)
{
    int gid = blockIdx.x * 256 + threadIdx.x;
    int e = gid >> 6, lane = gid & 63;
    if (e >= E) return;
    int t = tgt[e], s = src[e];
    float4 q = *(const float4*)(Q + (size_t)t * 256 + lane * 4);
    float4 k = *(const float4*)(K + (size_t)s * 256 + lane * 4);
    float acc = q.x * k.x + q.y * k.y + q.z * k.z + q.w * k.w;
    acc += __shfl_xor(acc, 1);
    acc += __shfl_xor(acc, 2);
    acc += __shfl_xor(acc, 4);
    acc += __shfl_xor(acc, 8);
    if ((lane & 15) == 0) {
        int h = lane >> 4;
        float sc = acc * 0.125f + logf(fmaxf(nw[e], 1e-10f));
        scores[(size_t)e * 4 + h] = sc;
        // smax init 0 == max(segment_max, 0); only positives matter, and
        // int-ordering == float-ordering for positive floats.
        if (sc > 0.f) atomicMax((int*)(smax + (size_t)t * 4 + h), __float_as_int(sc));
    }
}

// ---------- edge pass B: ex = exp(s - smax[tgt]); sumex += ex ----------
__global__ __launch_bounds__(256) void edge_expsum(
    const int* __restrict__ tgt, float* __restrict__ scores,
    const float* __restrict__ smax, float* __restrict__ sumex, int E4)
{
    int idx = blockIdx.x * 256 + threadIdx.x;
    if (idx >= E4) return;
    int e = idx >> 2, h = idx & 3;
    int t = tgt[e];
    float ex = expf(scores[idx] - smax[(size_t)t * 4 + h]);
    scores[idx] = ex;
    atomicAdd(sumex + (size_t)t * 4 + h, ex);
}

// ---------- edge pass C: msg[tgt] += attn * V[src] ----------
__global__ __launch_bounds__(256) void edge_scatter(
    const float* __restrict__ V, const int* __restrict__ tgt, const int* __restrict__ src,
    const float* __restrict__ ex, const float* __restrict__ sumex,
    float* __restrict__ msg, int E)
{
    int gid = blockIdx.x * 256 + threadIdx.x;
    int e = gid >> 6, lane = gid & 63;
    if (e >= E) return;
    int t = tgt[e], s = src[e], h = lane >> 4;
    float attn = ex[(size_t)e * 4 + h] / (sumex[(size_t)t * 4 + h] + 1e-10f);
    float4 v = *(const float4*)(V + (size_t)s * 256 + lane * 4);
    float* mp = msg + (size_t)t * 256 + lane * 4;
    atomicAdd(mp + 0, attn * v.x);
    atomicAdd(mp + 1, attn * v.y);
    atomicAdd(mp + 2, attn * v.z);
    atomicAdd(mp + 3, attn * v.w);
}

// ---------- host ----------
extern "C" void kernel_launch(void* const* d_in, const int* in_sizes, int n_in,
                              void* d_out, int out_size, void* d_ws, size_t ws_size,
                              hipStream_t stream) {
    const float* inv_h    = (const float*)d_in[0];
    const float* asset_h  = (const float*)d_in[1];
    const float* inv_nw   = (const float*)d_in[2];
    const float* asset_nw = (const float*)d_in[3];
    const float* m_w1 = (const float*)d_in[4];
    const float* m_b1 = (const float*)d_in[5];
    const float* m_w2 = (const float*)d_in[6];
    const float* m_b2 = (const float*)d_in[7];
    const float* Wq   = (const float*)d_in[8];
    const float* Wk   = (const float*)d_in[9];
    const float* Wv   = (const float*)d_in[10];
    const float* u_w1 = (const float*)d_in[11];
    const float* u_b1 = (const float*)d_in[12];
    const float* u_w2 = (const float*)d_in[13];
    const float* u_b2 = (const float*)d_in[14];
    const int* etgt  = (const int*)d_in[15];
    const int* esrc  = (const int*)d_in[16];

    const int I = in_sizes[0] / 256;
    const int A = in_sizes[1] / 256;
    const int E = in_sizes[15];

    // OUTPUT dtype is float32 (reference returns jnp.float32) — harness reads f32.
    float* out_inv   = (float*)d_out;
    float* out_asset = (float*)d_out + (size_t)I * 256;

    // workspace carve-up (256B aligned). Peak ~141 MB (all f32 intermediates).
    char* wsp = (char*)d_ws;
    size_t off = 0;
    auto alloc = [&](size_t bytes) -> void* {
        void* p = wsp + off;
        off += (bytes + 255) & ~(size_t)255;
        return p;
    };
    float* X1 = (float*)alloc((size_t)I * 256 * 4);  // t_i -> V_i -> Q_i -> hid_i
    float* X2 = (float*)alloc((size_t)I * 256 * 4);  // M_i -> K_i -> msg_i
    float* Y1 = (float*)alloc((size_t)A * 256 * 4);  // Q_a -> t_a -> V_a
    float* Y2 = (float*)alloc((size_t)A * 256 * 4);  // hid_a -> M_a -> K_a
    // contiguous accumulator block: msg_a, smax_i, sumex_i, smax_a, sumex_a
    float* msg_a  = (float*)alloc((size_t)A * 256 * 4);
    float* smax_i = (float*)alloc((size_t)I * 4 * 4);
    float* sumex_i= (float*)alloc((size_t)I * 4 * 4);
    float* smax_a = (float*)alloc((size_t)A * 4 * 4);
    float* sumex_a= (float*)alloc((size_t)A * 4 * 4);
    size_t accum_bytes = (char*)(sumex_a + (size_t)A * 4) - (char*)msg_a;
    float* scores = (float*)alloc((size_t)E * 4 * 4);
    float* msg_i = X2;  // reused after K_i is consumed (e1)

    hipMemsetAsync(msg_a, 0, accum_bytes, stream);

    auto g256 = [&](const float* A1, int M, const float* Wm, const float* bias,
                    float* Cm, int act) {
        dim3 grid((M + 3) / 4);
        if (act) hipLaunchKernelGGL((gemm_naive<256,1>), grid, dim3(256), 0, stream, A1, (const float*)nullptr, Wm, bias, Cm, M);
        else     hipLaunchKernelGGL((gemm_naive<256,0>), grid, dim3(256), 0, stream, A1, (const float*)nullptr, Wm, bias, Cm, M);
    };

    int eblocks  = (E * 64 + 255) / 256;
    int e4blocks = (E * 4 + 255) / 256;

    // ===== direction 2 first: assets aggregate from investors =====
    g256(inv_h, I, m_w1, m_b1, X1, 1);               // t_i
    g256(X1,    I, m_w2, m_b2, X2, 1);               // M_i
    g256(X2,    I, Wv, nullptr, X1, 0);              // V_i (X2=M_i consumed)
    g256(inv_h, I, Wk, nullptr, X2, 0);              // K_i
    g256(asset_h, A, Wq, nullptr, Y1, 0);            // Q_a

    hipLaunchKernelGGL(edge_scores, dim3(eblocks), dim3(256), 0, stream,
                       Y1, X2, esrc, etgt, asset_nw, scores, smax_a, E);  // e1
    hipLaunchKernelGGL(edge_expsum, dim3(e4blocks), dim3(256), 0, stream,
                       esrc, scores, smax_a, sumex_a, E * 4);             // e2
    hipLaunchKernelGGL(edge_scatter, dim3(eblocks), dim3(256), 0, stream,
                       X1, esrc, etgt, scores, sumex_a, msg_a, E);        // e3

    // asset update: out_asset = gelu(gelu(concat(asset_h,msg_a)@u_w1+u_b1)@u_w2+u_b2)
    hipLaunchKernelGGL((gemm_naive<512,1>), dim3((A + 3) / 4), dim3(256), 0, stream,
                       asset_h, msg_a, u_w1, u_b1, Y2, A);
    hipLaunchKernelGGL((gemm_naive<256,1>), dim3((A + 3) / 4), dim3(256), 0, stream,
                       Y2, (const float*)nullptr, u_w2, u_b2, out_asset, A);

    // msg_i reuses X2 (K_i consumed at e1): zero it now
    hipMemsetAsync(msg_i, 0, (size_t)I * 256 * 4, stream);

    // ===== direction 1: investors aggregate from assets =====
    g256(asset_h, A, m_w1, m_b1, Y1, 1);             // t_a (Q_a consumed)
    g256(Y1,      A, m_w2, m_b2, Y2, 1);             // M_a (hid_a consumed)
    g256(Y2,      A, Wv, nullptr, Y1, 0);            // V_a
    g256(asset_h, A, Wk, nullptr, Y2, 0);            // K_a
    g256(inv_h,   I, Wq, nullptr, X1, 0);            // Q_i (V_i consumed at e3)

    hipLaunchKernelGGL(edge_scores, dim3(eblocks), dim3(256), 0, stream,
                       X1, Y2, etgt, esrc, inv_nw, scores, smax_i, E);    // e4
    hipLaunchKernelGGL(edge_expsum, dim3(e4blocks), dim3(256), 0, stream,
                       etgt, scores, smax_i, sumex_i, E * 4);             // e5
    hipLaunchKernelGGL(edge_scatter, dim3(eblocks), dim3(256), 0, stream,
                       Y1, etgt, esrc, scores, sumex_i, msg_i, E);        // e6

    // inv update: out_inv = gelu(gelu(concat(inv_h,msg_i)@u_w1+u_b1)@u_w2+u_b2)
    hipLaunchKernelGGL((gemm_naive<512,1>), dim3((I + 3) / 4), dim3(256), 0, stream,
                       inv_h, msg_i, u_w1, u_b1, X1, I);                  // X1=Q_i consumed at e4
    hipLaunchKernelGGL((gemm_naive<256,1>), dim3((I + 3) / 4), dim3(256), 0, stream,
                       X1, (const float*)nullptr, u_w2, u_b2, out_inv, I);
}

// Round 7
// 1351.630 us; speedup vs baseline: 2.3275x; 2.3275x over previous
//
#include <hip/hip_runtime.h>
#include <hip/hip_bf16.h>

// ---------- helpers ----------
__device__ __forceinline__ float gelu_exact(float x) {
    return 0.5f * x * (1.0f + erff(x * 0.70710678118654752440f));
}

// ================= CSR build =================
__global__ __launch_bounds__(256) void count_kernel(
    const int* __restrict__ tgt, const int* __restrict__ src,
    int* __restrict__ cnt_i, int* __restrict__ cnt_a, int E)
{
    int e = blockIdx.x * 256 + threadIdx.x;
    if (e < E) {
        atomicAdd(&cnt_i[tgt[e]], 1);
        atomicAdd(&cnt_a[src[e]], 1);
    }
}

// exclusive scan within 256-blocks; block totals to bsum
__global__ __launch_bounds__(256) void scan_block(
    const int* __restrict__ cnt, int* __restrict__ offs, int* __restrict__ bsum, int N)
{
    __shared__ int s[256];
    int i = blockIdx.x * 256 + threadIdx.x;
    int v = (i < N) ? cnt[i] : 0;
    s[threadIdx.x] = v;
    __syncthreads();
    for (int d = 1; d < 256; d <<= 1) {
        int t = (threadIdx.x >= d) ? s[threadIdx.x - d] : 0;
        __syncthreads();
        s[threadIdx.x] += t;
        __syncthreads();
    }
    if (i < N) offs[i] = s[threadIdx.x] - v;   // exclusive
    if (threadIdx.x == 255) bsum[blockIdx.x] = s[255];
}

// single-block exclusive scan of block sums (nb <= 256)
__global__ __launch_bounds__(256) void scan_bsum(int* __restrict__ bsum, int nb)
{
    __shared__ int s[256];
    int v = (threadIdx.x < nb) ? bsum[threadIdx.x] : 0;
    s[threadIdx.x] = v;
    __syncthreads();
    for (int d = 1; d < 256; d <<= 1) {
        int t = (threadIdx.x >= d) ? s[threadIdx.x - d] : 0;
        __syncthreads();
        s[threadIdx.x] += t;
        __syncthreads();
    }
    if (threadIdx.x < nb) bsum[threadIdx.x] = s[threadIdx.x] - v;  // exclusive
}

// offs += block offset; cursor = final offs; offs[N] = E
__global__ __launch_bounds__(256) void add_offs(
    int* __restrict__ offs, int* __restrict__ cursor,
    const int* __restrict__ bsum, int N, int E)
{
    int i = blockIdx.x * 256 + threadIdx.x;
    if (i < N) {
        int f = offs[i] + bsum[blockIdx.x];
        offs[i] = f;
        cursor[i] = f;
    }
    if (i == 0) offs[N] = E;
}

__global__ __launch_bounds__(256) void fill_kernel(
    const int* __restrict__ tgt, const int* __restrict__ src,
    int* __restrict__ cur_i, int* __restrict__ cur_a,
    int* __restrict__ eid_i, int* __restrict__ eid_a, int E)
{
    int e = blockIdx.x * 256 + threadIdx.x;
    if (e < E) {
        int p = atomicAdd(&cur_i[tgt[e]], 1);
        eid_i[p] = e;
        int q = atomicAdd(&cur_a[src[e]], 1);
        eid_a[q] = e;
    }
}

// ================= fused per-target attention =================
// one wave per target t: pass1 scores->scbuf + max; pass2 exp/sum + ex*V accumulate.
// lane covers dims [4*lane, 4*lane+4); head h = lane>>4 (dims 64h..64h+63).
__global__ __launch_bounds__(256) void fused_attn(
    const float* __restrict__ Q, const float* __restrict__ Kk, const float* __restrict__ V,
    const int* __restrict__ offs, const int* __restrict__ eids,
    const int* __restrict__ other, const float* __restrict__ nw,
    float* __restrict__ scbuf, float* __restrict__ msg, int T)
{
    int w = blockIdx.x * 4 + (threadIdx.x >> 6);
    int lane = threadIdx.x & 63;
    if (w >= T) return;
    int t = w;
    int beg = offs[t], end = offs[t + 1];
    int h = lane >> 4;

    float4 q = *(const float4*)(Q + (size_t)t * 256 + lane * 4);

    float mx = 0.f;   // init 0 == torch scatter_reduce amax include_self with zeros
    for (int j = beg; j < end; ++j) {
        int e = eids[j];
        int s = other[e];
        float4 k = *(const float4*)(Kk + (size_t)s * 256 + lane * 4);
        float d = q.x * k.x + q.y * k.y + q.z * k.z + q.w * k.w;
        d += __shfl_xor(d, 1);
        d += __shfl_xor(d, 2);
        d += __shfl_xor(d, 4);
        d += __shfl_xor(d, 8);       // all 16 lanes of the group hold the head dot
        float sc = d * 0.125f + logf(fmaxf(nw[e], 1e-10f));
        if ((lane & 15) == 0) scbuf[(size_t)j * 4 + h] = sc;
        mx = fmaxf(mx, sc);
    }

    float sum = 0.f;
    float4 macc = make_float4(0.f, 0.f, 0.f, 0.f);
    for (int j = beg; j < end; ++j) {
        int e = eids[j];
        int s = other[e];
        float sc = scbuf[(size_t)j * 4 + h];
        float ex = expf(sc - mx);
        sum += ex;
        float4 v = *(const float4*)(V + (size_t)s * 256 + lane * 4);
        macc.x += ex * v.x; macc.y += ex * v.y;
        macc.z += ex * v.z; macc.w += ex * v.w;
    }
    float inv = 1.f / (sum + 1e-10f);
    *(float4*)(msg + (size_t)t * 256 + lane * 4) =
        make_float4(macc.x * inv, macc.y * inv, macc.z * inv, macc.w * inv);
}

// ================= tiled GEMM =================
// C[M,256] = act(concat(A1,A2)[M,K] @ W[K,256] + bias); K=256 (CONCAT=0) or 512.
// 64x64 tile, BK=32, 256 threads, 4x4 per-thread acc, f32 throughout.
template<int CONCAT>
__global__ __launch_bounds__(256) void gemm_tiled(
    const float* __restrict__ A1, const float* __restrict__ A2,
    const float* __restrict__ W, const float* __restrict__ bias,
    float* __restrict__ C, int M, int act)
{
    const int K = CONCAT ? 512 : 256;
    const int N = 256;
    __shared__ float As[32][68];   // [k][m]
    __shared__ float Ws[32][68];   // [k][n]

    int tid = threadIdx.x;
    int tx = tid & 15, ty = tid >> 4;
    int bm = blockIdx.y * 64;
    int bn = blockIdx.x * 64;

    int ar = tid >> 2;            // 0..63  (A tile row)
    int ak = (tid & 3) * 8;       // 0/8/16/24 (A tile k-offset)
    int wr = tid >> 3;            // 0..31  (W tile k-row)
    int wn = (tid & 7) * 8;       // 0..56  (W tile n-offset)

    float acc[4][4] = {};

    for (int k0 = 0; k0 < K; k0 += 32) {
        {   // stage A tile (BK=32 tile wholly from one source)
            int row = bm + ar;
            float4 f0 = make_float4(0.f, 0.f, 0.f, 0.f), f1 = f0;
            if (row < M) {
                const float* p = (CONCAT && k0 >= 256)
                    ? (A2 + (size_t)row * 256 + (k0 - 256) + ak)
                    : (A1 + (size_t)row * 256 + k0 + ak);
                f0 = *(const float4*)(p);
                f1 = *(const float4*)(p + 4);
            }
            As[ak + 0][ar] = f0.x; As[ak + 1][ar] = f0.y;
            As[ak + 2][ar] = f0.z; As[ak + 3][ar] = f0.w;
            As[ak + 4][ar] = f1.x; As[ak + 5][ar] = f1.y;
            As[ak + 6][ar] = f1.z; As[ak + 7][ar] = f1.w;
        }
        {   // stage W tile
            const float* wp = W + (size_t)(k0 + wr) * N + bn + wn;
            float4 w0 = *(const float4*)(wp);
            float4 w1 = *(const float4*)(wp + 4);
            Ws[wr][wn + 0] = w0.x; Ws[wr][wn + 1] = w0.y;
            Ws[wr][wn + 2] = w0.z; Ws[wr][wn + 3] = w0.w;
            Ws[wr][wn + 4] = w1.x; Ws[wr][wn + 5] = w1.y;
            Ws[wr][wn + 6] = w1.z; Ws[wr][wn + 7] = w1.w;
        }
        __syncthreads();

        #pragma unroll
        for (int kk = 0; kk < 32; kk++) {
            float4 av = *(const float4*)&As[kk][ty * 4];
            float4 wv = *(const float4*)&Ws[kk][tx * 4];
            acc[0][0] += av.x * wv.x; acc[0][1] += av.x * wv.y; acc[0][2] += av.x * wv.z; acc[0][3] += av.x * wv.w;
            acc[1][0] += av.y * wv.x; acc[1][1] += av.y * wv.y; acc[1][2] += av.y * wv.z; acc[1][3] += av.y * wv.w;
            acc[2][0] += av.z * wv.x; acc[2][1] += av.z * wv.y; acc[2][2] += av.z * wv.z; acc[2][3] += av.z * wv.w;
            acc[3][0] += av.w * wv.x; acc[3][1] += av.w * wv.y; acc[3][2] += av.w * wv.z; acc[3][3] += av.w * wv.w;
        }
        __syncthreads();
    }

    float bv[4] = {0.f, 0.f, 0.f, 0.f};
    if (bias) {
        const float* bp = bias + bn + tx * 4;
        bv[0] = bp[0]; bv[1] = bp[1]; bv[2] = bp[2]; bv[3] = bp[3];
    }
    #pragma unroll
    for (int i = 0; i < 4; i++) {
        int row = bm + ty * 4 + i;
        if (row >= M) continue;
        float c0 = acc[i][0] + bv[0];
        float c1 = acc[i][1] + bv[1];
        float c2 = acc[i][2] + bv[2];
        float c3 = acc[i][3] + bv[3];
        if (act) { c0 = gelu_exact(c0); c1 = gelu_exact(c1); c2 = gelu_exact(c2); c3 = gelu_exact(c3); }
        *(float4*)(C + (size_t)row * N + bn + tx * 4) = make_float4(c0, c1, c2, c3);
    }
}

// ================= host =================
extern "C" void kernel_launch(void* const* d_in, const int* in_sizes, int n_in,
                              void* d_out, int out_size, void* d_ws, size_t ws_size,
                              hipStream_t stream) {
    const float* inv_h    = (const float*)d_in[0];
    const float* asset_h  = (const float*)d_in[1];
    const float* inv_nw   = (const float*)d_in[2];
    const float* asset_nw = (const float*)d_in[3];
    const float* m_w1 = (const float*)d_in[4];
    const float* m_b1 = (const float*)d_in[5];
    const float* m_w2 = (const float*)d_in[6];
    const float* m_b2 = (const float*)d_in[7];
    const float* Wq   = (const float*)d_in[8];
    const float* Wk   = (const float*)d_in[9];
    const float* Wv   = (const float*)d_in[10];
    const float* u_w1 = (const float*)d_in[11];
    const float* u_b1 = (const float*)d_in[12];
    const float* u_w2 = (const float*)d_in[13];
    const float* u_b2 = (const float*)d_in[14];
    const int* etgt  = (const int*)d_in[15];
    const int* esrc  = (const int*)d_in[16];

    const int I = in_sizes[0] / 256;
    const int A = in_sizes[1] / 256;
    const int E = in_sizes[15];

    float* out_inv   = (float*)d_out;
    float* out_asset = (float*)d_out + (size_t)I * 256;

    // workspace carve-up (256B aligned). Peak ~130 MB.
    char* wsp = (char*)d_ws;
    size_t off = 0;
    auto alloc = [&](size_t bytes) -> void* {
        void* p = wsp + off;
        off += (bytes + 255) & ~(size_t)255;
        return p;
    };
    float* X1 = (float*)alloc((size_t)I * 256 * 4);  // t_i -> V_i -> Q_i -> hid_i
    float* X2 = (float*)alloc((size_t)I * 256 * 4);  // M_i -> K_i -> msg_i
    float* Y1 = (float*)alloc((size_t)A * 256 * 4);  // Q_a -> t_a -> V_a
    float* Y2 = (float*)alloc((size_t)A * 256 * 4);  // hid_a -> M_a -> K_a
    float* msg_a = (float*)alloc((size_t)A * 256 * 4);
    float* scbuf = (float*)alloc((size_t)E * 4 * 4);
    // CSR: cnt arrays contiguous (one memset); cnt doubles as cursor after scan
    int* cnt_i  = (int*)alloc((size_t)I * 4);
    int* cnt_a  = (int*)alloc((size_t)A * 4);
    int* offs_i = (int*)alloc((size_t)(I + 1) * 4);
    int* offs_a = (int*)alloc((size_t)(A + 1) * 4);
    int* eid_i  = (int*)alloc((size_t)E * 4);
    int* eid_a  = (int*)alloc((size_t)E * 4);
    int* bsum_i = (int*)alloc(256 * 4);
    int* bsum_a = (int*)alloc(256 * 4);
    float* msg_i = X2;   // overlays X2 (K_i dead before msg_i written)

    const int nbI = (I + 255) / 256;   // 196 <= 256
    const int nbA = (A + 255) / 256;   // 40  <= 256
    const int nbE = (E + 255) / 256;

    // ---- CSR build (both directions) ----
    hipMemsetAsync(cnt_i, 0, ((size_t)I + A) * 4 + 256 /*padding safe: cnt_a follows*/ - 256, stream);
    hipMemsetAsync(cnt_a, 0, (size_t)A * 4, stream);
    hipLaunchKernelGGL(count_kernel, dim3(nbE), dim3(256), 0, stream,
                       etgt, esrc, cnt_i, cnt_a, E);
    hipLaunchKernelGGL(scan_block, dim3(nbI), dim3(256), 0, stream, cnt_i, offs_i, bsum_i, I);
    hipLaunchKernelGGL(scan_block, dim3(nbA), dim3(256), 0, stream, cnt_a, offs_a, bsum_a, A);
    hipLaunchKernelGGL(scan_bsum, dim3(1), dim3(256), 0, stream, bsum_i, nbI);
    hipLaunchKernelGGL(scan_bsum, dim3(1), dim3(256), 0, stream, bsum_a, nbA);
    hipLaunchKernelGGL(add_offs, dim3(nbI), dim3(256), 0, stream, offs_i, cnt_i, bsum_i, I, E);
    hipLaunchKernelGGL(add_offs, dim3(nbA), dim3(256), 0, stream, offs_a, cnt_a, bsum_a, A, E);
    hipLaunchKernelGGL(fill_kernel, dim3(nbE), dim3(256), 0, stream,
                       etgt, esrc, cnt_i, cnt_a, eid_i, eid_a, E);

    auto gemm = [&](const float* A1, const float* A2, int M, const float* Wm,
                    const float* bias, float* Cm, int act, int concat) {
        dim3 grid(4, (M + 63) / 64);
        if (concat) hipLaunchKernelGGL((gemm_tiled<1>), grid, dim3(256), 0, stream, A1, A2, Wm, bias, Cm, M, act);
        else        hipLaunchKernelGGL((gemm_tiled<0>), grid, dim3(256), 0, stream, A1, A2, Wm, bias, Cm, M, act);
    };

    // ===== direction 2: assets aggregate from investors (segments = esrc) =====
    gemm(inv_h, nullptr, I, m_w1, m_b1, X1, 1, 0);   // t_i
    gemm(X1,    nullptr, I, m_w2, m_b2, X2, 1, 0);   // M_i
    gemm(X2,    nullptr, I, Wv, nullptr, X1, 0, 0);  // V_i
    gemm(inv_h, nullptr, I, Wk, nullptr, X2, 0, 0);  // K_i
    gemm(asset_h, nullptr, A, Wq, nullptr, Y1, 0, 0);// Q_a

    hipLaunchKernelGGL(fused_attn, dim3((A + 3) / 4), dim3(256), 0, stream,
                       Y1, X2, X1, offs_a, eid_a, etgt, asset_nw, scbuf, msg_a, A);

    gemm(asset_h, msg_a, A, u_w1, u_b1, Y2, 1, 1);   // hid_a (Q_a dead)
    gemm(Y2, nullptr, A, u_w2, u_b2, out_asset, 1, 0);

    // ===== direction 1: investors aggregate from assets (segments = etgt) =====
    gemm(asset_h, nullptr, A, m_w1, m_b1, Y1, 1, 0); // t_a
    gemm(Y1,      nullptr, A, m_w2, m_b2, Y2, 1, 0); // M_a (hid_a dead)
    gemm(Y2,      nullptr, A, Wv, nullptr, Y1, 0, 0);// V_a (t_a dead)
    gemm(asset_h, nullptr, A, Wk, nullptr, Y2, 0, 0);// K_a (M_a dead)
    gemm(inv_h,   nullptr, I, Wq, nullptr, X1, 0, 0);// Q_i (V_i dead)

    hipLaunchKernelGGL(fused_attn, dim3((I + 3) / 4), dim3(256), 0, stream,
                       X1, Y2, Y1, offs_i, eid_i, esrc, inv_nw, scbuf, msg_i, I);

    gemm(inv_h, msg_i, I, u_w1, u_b1, X1, 1, 1);     // hid_i (Q_i dead)
    gemm(X1, nullptr, I, u_w2, u_b2, out_inv, 1, 0);
}